// Round 7
// baseline (509.780 us; speedup 1.0000x reference)
//
#include <hip/hip_runtime.h>

// EnhancedGNN on MI355X.
// R10: stats fusion reverted (R8/R9 both lost: atomic tail + 2x WRITE_SIZE).
//      mm kernels rebuilt barrier-free: x/G row chunks (16 k) in REGISTERS
//      (4 waves share rows via L1), W wave-uniform via readfirstlane -> s_load,
//      no LDS staging, no phase-sync barriers (one scl barrier + one aliasing
//      barrier in mmB). VGPR ~55-60 (under the 64 cliff). agg64/stats = R7
//      shapes (best measured). 16 launches.

#define NN 100000
#define NE 1200000
#define NBATCH 64
#define IND 128
#define HID 64
#define EPSF 1e-5f
#define NBUCK 782   // ceil(100000/128)
#define NPB 128     // nodes per bucket; bucket(d) = d >> 7

// ---------------- graph prep: bucket histogram ----------------
__global__ void k_ehist(const int* __restrict__ dst, int* __restrict__ gbh) {
  __shared__ int lh[NBUCK];
  int tid = threadIdx.x;
  for (int i = tid; i < NBUCK; i += 256) lh[i] = 0;
  __syncthreads();
  int base = blockIdx.x * 4096;
#pragma unroll
  for (int j = 0; j < 16; j++) {
    int e = base + j * 256 + tid;
    if (e < NE) atomicAdd(&lh[dst[e] >> 7], 1);
  }
  __syncthreads();
  for (int i = tid; i < NBUCK; i += 256) {
    int v = lh[i];
    if (v) atomicAdd(&gbh[i], v);
  }
}

// exclusive scan of 782 bucket counts -> bbase[0..NBUCK], bcur=bbase
__global__ void k_escan(const int* __restrict__ gbh, int* __restrict__ bbase,
                        int* __restrict__ bcur) {
  __shared__ int a[256];
  int tid = threadIdx.x;
  int loc[4];
  int tsum = 0;
  for (int j = 0; j < 4; j++) {
    int idx = tid * 4 + j;
    int v = (idx < NBUCK) ? gbh[idx] : 0;
    loc[j] = tsum;
    tsum += v;
  }
  a[tid] = tsum;
  __syncthreads();
  for (int off = 1; off < 256; off <<= 1) {
    int v = (tid >= off) ? a[tid - off] : 0;
    __syncthreads();
    a[tid] += v;
    __syncthreads();
  }
  int excl = a[tid] - tsum;
  for (int j = 0; j < 4; j++) {
    int idx = tid * 4 + j;
    if (idx < NBUCK) {
      int v = excl + loc[j];
      bbase[idx] = v;
      bcur[idx] = v;
    }
  }
  if (tid == 255) bbase[NBUCK] = a[255];
}

// scatter (src,dst) pairs into bucket-contiguous ebuf; LDS-aggregated cursor grabs
__global__ void k_escatter(const int* __restrict__ src, const int* __restrict__ dst,
                           int* __restrict__ bcur, unsigned long long* __restrict__ ebuf) {
  __shared__ int lh[NBUCK];
  __shared__ int lbase[NBUCK];
  int tid = threadIdx.x;
  for (int i = tid; i < NBUCK; i += 256) lh[i] = 0;
  __syncthreads();
  int base = blockIdx.x * 4096;
  int sv[16], dv[16], rk[16];
#pragma unroll
  for (int j = 0; j < 16; j++) {
    int e = base + j * 256 + tid;
    if (e < NE) {
      sv[j] = src[e];
      dv[j] = dst[e];
      rk[j] = atomicAdd(&lh[dv[j] >> 7], 1);
    } else {
      dv[j] = -1;
    }
  }
  __syncthreads();
  for (int i = tid; i < NBUCK; i += 256) {
    int v = lh[i];
    lbase[i] = v ? atomicAdd(&bcur[i], v) : 0;
  }
  __syncthreads();
#pragma unroll
  for (int j = 0; j < 16; j++) {
    if (dv[j] >= 0) {
      int b = dv[j] >> 7;
      ebuf[lbase[b] + rk[j]] =
          (unsigned long long)(unsigned)sv[j] | ((unsigned long long)(unsigned)dv[j] << 32);
    }
  }
}

// one block per bucket: local hist -> deg/dinv, local scan -> rowp, LDS-cursor fill -> col
__global__ void k_bucket_csr(const unsigned long long* __restrict__ ebuf,
                             const int* __restrict__ bbase, int* __restrict__ deg,
                             int* __restrict__ rowp, float* __restrict__ dinv,
                             int* __restrict__ col) {
  __shared__ int ldeg[NPB];
  __shared__ int lcur[NPB];
  __shared__ int sred[NPB];
  int b = blockIdx.x, tid = threadIdx.x;
  int nbase = b * NPB;
  int e0 = bbase[b], e1 = bbase[b + 1];
  if (tid < NPB) ldeg[tid] = 0;
  __syncthreads();
  for (int e = e0 + tid; e < e1; e += 256) {
    int d = (int)(ebuf[e] >> 32) - nbase;
    atomicAdd(&ldeg[d], 1);
  }
  __syncthreads();
  if (tid < NPB) sred[tid] = ldeg[tid];
  __syncthreads();
  for (int off = 1; off < NPB; off <<= 1) {
    int v = 0;
    if (tid < NPB && tid >= off) v = sred[tid - off];
    __syncthreads();
    if (tid < NPB) sred[tid] += v;
    __syncthreads();
  }
  if (tid < NPB) {
    int excl = sred[tid] - ldeg[tid];
    lcur[tid] = excl;
    int gn = nbase + tid;
    if (gn < NN) {
      int dg = ldeg[tid];
      deg[gn] = dg;
      rowp[gn] = e0 + excl;
      dinv[gn] = rsqrtf((float)dg + 1.0f);
    }
  }
  __syncthreads();
  for (int e = e0 + tid; e < e1; e += 256) {
    unsigned long long p = ebuf[e];
    int s = (int)(unsigned)p;
    int d = (int)(p >> 32) - nbase;
    int r = atomicAdd(&lcur[d], 1);
    col[e0 + r] = s;
  }
}

// ---------------- mm A: X[nrows,128] @ W[128,64] -> T * dinv[row] --------------
// Barrier-free: 64 rows/block, 4 threads/row (quarter per WAVE, readfirstlane ->
// s_load W). Row k-chunks (16) live in registers; 4 waves share rows via L1.
__global__ __launch_bounds__(256) void k_mmA(const float* __restrict__ X,
                                             const float* __restrict__ W,
                                             const float* __restrict__ dinv,
                                             float* __restrict__ T, int nrows) {
  int tid = threadIdx.x;
  int q4 = __builtin_amdgcn_readfirstlane(tid >> 6);  // wave-uniform col quarter
  int r = tid & 63;
  int row = blockIdx.x * 64 + r;
  int rowc = row < nrows ? row : nrows - 1;
  const float4* xp = (const float4*)(X + (size_t)rowc * 128);
  const float* Wq = W + q4 * 16;
  float4 acc[4];
#pragma unroll
  for (int j = 0; j < 4; j++) acc[j] = {0.f, 0.f, 0.f, 0.f};

#pragma unroll
  for (int ch = 0; ch < 8; ch++) {
    float4 xv[4];
#pragma unroll
    for (int i = 0; i < 4; i++) xv[i] = xp[ch * 4 + i];
#pragma unroll
    for (int kk = 0; kk < 16; kk++) {
      float xk = ((const float*)xv)[kk];
      const float4* wr = (const float4*)(Wq + (size_t)(ch * 16 + kk) * 64);
#pragma unroll
      for (int j = 0; j < 4; j++) {
        float4 wv = wr[j];
        acc[j].x = fmaf(xk, wv.x, acc[j].x);
        acc[j].y = fmaf(xk, wv.y, acc[j].y);
        acc[j].z = fmaf(xk, wv.z, acc[j].z);
        acc[j].w = fmaf(xk, wv.w, acc[j].w);
      }
    }
  }

  if (row < nrows) {
    float dv = dinv[row];
    float4* t4 = (float4*)(T + (size_t)row * 64 + q4 * 16);
#pragma unroll
    for (int j = 0; j < 4; j++) {
      float4 o = acc[j];
      o.x *= dv; o.y *= dv; o.z *= dv; o.w *= dv;
      t4[j] = o;
    }
  }
}

// ---------------- mm B: BN(G)(+res) -> Hside; T = (h @ W) * dinv[row] ----------
// Same barrier-free structure; BN-apply in registers per 16-k chunk; Hside chunk
// written by wave q4==ch (each element exactly once). One barrier before T store
// preserves layer-3 G==T aliasing safety.
__global__ __launch_bounds__(256) void k_mmB(const float* __restrict__ G,
                                             const double* __restrict__ st,
                                             const float* __restrict__ gamma,
                                             const float* __restrict__ beta,
                                             const float* __restrict__ res,
                                             float* __restrict__ Hside,
                                             const float* __restrict__ W,
                                             const float* __restrict__ dinv,
                                             float* __restrict__ T, int nrows) {
  __shared__ float scl[128];
  int tid = threadIdx.x;
  if (tid < 64) {
    double m = st[tid] / (double)NN;
    double var = st[64 + tid] / (double)NN - m * m;
    float scale = gamma[tid] * rsqrtf((float)var + EPSF);
    scl[tid] = scale;
    scl[64 + tid] = beta[tid] - (float)m * scale;
  }
  __syncthreads();

  int q4 = __builtin_amdgcn_readfirstlane(tid >> 6);
  int r = tid & 63;
  int row = blockIdx.x * 64 + r;
  int rowc = row < nrows ? row : nrows - 1;
  const float4* gp = (const float4*)(G + (size_t)rowc * 64);
  const float4* rp = (res != nullptr) ? (const float4*)(res + (size_t)rowc * 64) : nullptr;
  float4 acc[4];
#pragma unroll
  for (int j = 0; j < 4; j++) acc[j] = {0.f, 0.f, 0.f, 0.f};

#pragma unroll
  for (int ch = 0; ch < 4; ch++) {
    float4 hv[4];
#pragma unroll
    for (int i = 0; i < 4; i++) {
      int kq = ch * 4 + i;
      float4 v = gp[kq];
      float4 s = ((const float4*)scl)[kq];
      float4 sh = ((const float4*)(scl + 64))[kq];
      v.x = v.x * s.x + sh.x;
      v.y = v.y * s.y + sh.y;
      v.z = v.z * s.z + sh.z;
      v.w = v.w * s.w + sh.w;
      if (rp != nullptr) {
        float4 rr = rp[kq];
        v.x += rr.x; v.y += rr.y; v.z += rr.z; v.w += rr.w;
      }
      hv[i] = v;
    }
    if (q4 == ch && row < nrows) {  // wave-uniform: wave ch owns Hside chunk ch
      float4* hp = (float4*)(Hside + (size_t)row * 64 + ch * 16);
#pragma unroll
      for (int i = 0; i < 4; i++) hp[i] = hv[i];
    }
#pragma unroll
    for (int kk = 0; kk < 16; kk++) {
      float xk = ((const float*)hv)[kk];
      const float4* wr = (const float4*)(W + (size_t)(ch * 16 + kk) * 64 + q4 * 16);
#pragma unroll
      for (int j = 0; j < 4; j++) {
        float4 wv = wr[j];
        acc[j].x = fmaf(xk, wv.x, acc[j].x);
        acc[j].y = fmaf(xk, wv.y, acc[j].y);
        acc[j].z = fmaf(xk, wv.z, acc[j].z);
        acc[j].w = fmaf(xk, wv.w, acc[j].w);
      }
    }
  }

  __syncthreads();  // all G reads complete before any T store (layer-3 G==T alias)

  if (row < nrows) {
    float dv = dinv[row];
    float4* t4 = (float4*)(T + (size_t)row * 64 + q4 * 16);
#pragma unroll
    for (int j = 0; j < 4; j++) {
      float4 o = acc[j];
      o.x *= dv; o.y *= dv; o.z *= dv; o.w *= dv;
      t4[j] = o;
    }
  }
}

// ---------------- aggregation (HID=64): wave/node, 16 edges in flight --------------
// T is pre-scaled by dinv[row]: o = di*(sum T'[src] + T'[node]) + bias
__global__ void k_agg64(const float* __restrict__ T, const int* __restrict__ row_start,
                        const int* __restrict__ cnt, const int* __restrict__ col,
                        const float* __restrict__ dinv, const float* __restrict__ bias,
                        float* __restrict__ G, int relu) {
  int lane = threadIdx.x & 63;
  int wv = threadIdx.x >> 6;
  int node = blockIdx.x * 4 + wv;
  if (node >= NN) return;
  int grp = lane >> 4;
  int q = lane & 15;
  int s = row_start[node];
  int c = cnt[node];
  float4 acc = {0.f, 0.f, 0.f, 0.f};
  for (int i = 0; i < c; i += 16) {
    int j0 = i + grp, j1 = j0 + 4, j2 = j0 + 8, j3 = j0 + 12;
    int s0 = col[s + (j0 < c ? j0 : 0)];
    int s1 = col[s + (j1 < c ? j1 : 0)];
    int s2 = col[s + (j2 < c ? j2 : 0)];
    int s3 = col[s + (j3 < c ? j3 : 0)];
    float4 t0 = ((const float4*)(T + (size_t)s0 * 64))[q];
    float4 t1 = ((const float4*)(T + (size_t)s1 * 64))[q];
    float4 t2 = ((const float4*)(T + (size_t)s2 * 64))[q];
    float4 t3 = ((const float4*)(T + (size_t)s3 * 64))[q];
    float w0 = j0 < c ? 1.f : 0.f;
    float w1 = j1 < c ? 1.f : 0.f;
    float w2 = j2 < c ? 1.f : 0.f;
    float w3 = j3 < c ? 1.f : 0.f;
    acc.x = fmaf(w0, t0.x, acc.x); acc.y = fmaf(w0, t0.y, acc.y);
    acc.z = fmaf(w0, t0.z, acc.z); acc.w = fmaf(w0, t0.w, acc.w);
    acc.x = fmaf(w1, t1.x, acc.x); acc.y = fmaf(w1, t1.y, acc.y);
    acc.z = fmaf(w1, t1.z, acc.z); acc.w = fmaf(w1, t1.w, acc.w);
    acc.x = fmaf(w2, t2.x, acc.x); acc.y = fmaf(w2, t2.y, acc.y);
    acc.z = fmaf(w2, t2.z, acc.z); acc.w = fmaf(w2, t2.w, acc.w);
    acc.x = fmaf(w3, t3.x, acc.x); acc.y = fmaf(w3, t3.y, acc.y);
    acc.z = fmaf(w3, t3.z, acc.z); acc.w = fmaf(w3, t3.w, acc.w);
  }
  acc.x += __shfl_xor(acc.x, 16, 64);
  acc.y += __shfl_xor(acc.y, 16, 64);
  acc.z += __shfl_xor(acc.z, 16, 64);
  acc.w += __shfl_xor(acc.w, 16, 64);
  acc.x += __shfl_xor(acc.x, 32, 64);
  acc.y += __shfl_xor(acc.y, 32, 64);
  acc.z += __shfl_xor(acc.z, 32, 64);
  acc.w += __shfl_xor(acc.w, 32, 64);
  if (grp == 0) {
    float di = dinv[node];
    float4 ts = ((const float4*)(T + (size_t)node * 64))[q];
    float4 bs = ((const float4*)bias)[q];
    float4 o;
    o.x = (acc.x + ts.x) * di + bs.x;
    o.y = (acc.y + ts.y) * di + bs.y;
    o.z = (acc.z + ts.z) * di + bs.z;
    o.w = (acc.w + ts.w) * di + bs.w;
    if (relu) {
      o.x = fmaxf(o.x, 0.f);
      o.y = fmaxf(o.y, 0.f);
      o.z = fmaxf(o.z, 0.f);
      o.w = fmaxf(o.w, 0.f);
    }
    ((float4*)(G + (size_t)node * 64))[q] = o;
  }
}

// ---------------- BN stats ----------------
__global__ void k_stats(const float* __restrict__ H, double* __restrict__ st) {
  int f = threadIdx.x & 63;
  int g = threadIdx.x >> 6;
  float s1 = 0.f, s2 = 0.f;
  for (int r = blockIdx.x * 4 + g; r < NN; r += gridDim.x * 4) {
    float v = H[(size_t)r * 64 + f];
    s1 += v;
    s2 += v * v;
  }
  __shared__ float a[256], b[256];
  a[threadIdx.x] = s1;
  b[threadIdx.x] = s2;
  __syncthreads();
  if (threadIdx.x < 64) {
    float t1 = a[f] + a[f + 64] + a[f + 128] + a[f + 192];
    float t2 = b[f] + b[f + 64] + b[f + 128] + b[f + 192];
    unsafeAtomicAdd(&st[f], (double)t1);
    unsafeAtomicAdd(&st[64 + f], (double)t2);
  }
}

// ---------------- fused: BN3 (in-block scale) + residual + matmul 64->2, T2 *= dinv --
__global__ void k_bnmmout(const float* __restrict__ G, const double* __restrict__ st,
                          const float* __restrict__ gamma, const float* __restrict__ beta,
                          const float* __restrict__ res, const float* __restrict__ W,
                          const float* __restrict__ dinv, float* __restrict__ T2,
                          int nrows) {
  __shared__ float Wl[128];
  __shared__ float scl[128];
  int tid = threadIdx.x;
  if (tid < 32) ((float4*)Wl)[tid] = ((const float4*)W)[tid];
  else if (tid >= 64 && tid < 128) {
    int f = tid - 64;
    double m = st[f] / (double)NN;
    double var = st[64 + f] / (double)NN - m * m;
    float scale = gamma[f] * rsqrtf((float)var + EPSF);
    scl[f] = scale;
    scl[64 + f] = beta[f] - (float)m * scale;
  }
  __syncthreads();
  int row = blockIdx.x * 256 + tid;
  if (row >= nrows) return;
  const float4* g4 = (const float4*)(G + (size_t)row * 64);
  const float4* r4 = (const float4*)(res + (size_t)row * 64);
  float a0 = 0.f, a1 = 0.f;
#pragma unroll
  for (int q = 0; q < 16; q++) {
    float4 v = g4[q];
    float4 rr = r4[q];
    float4 s = ((const float4*)scl)[q];
    float4 sh = ((const float4*)(scl + 64))[q];
    float h0 = v.x * s.x + sh.x + rr.x;
    float h1 = v.y * s.y + sh.y + rr.y;
    float h2 = v.z * s.z + sh.z + rr.z;
    float h3 = v.w * s.w + sh.w + rr.w;
    const float* wk = Wl + q * 8;
    a0 = fmaf(h0, wk[0], a0); a1 = fmaf(h0, wk[1], a1);
    a0 = fmaf(h1, wk[2], a0); a1 = fmaf(h1, wk[3], a1);
    a0 = fmaf(h2, wk[4], a0); a1 = fmaf(h2, wk[5], a1);
    a0 = fmaf(h3, wk[6], a0); a1 = fmaf(h3, wk[7], a1);
  }
  float dv = dinv[row];
  T2[(size_t)row * 2 + 0] = a0 * dv;
  T2[(size_t)row * 2 + 1] = a1 * dv;
}

// ---- fused final aggregation (dim 2, T2 pre-scaled) + pool: thread/node, float2 ----
__global__ void k_agg2pool(const float* __restrict__ T2, const int* __restrict__ rowp,
                           const int* __restrict__ cnt, const int* __restrict__ col,
                           const float* __restrict__ dinv, const float* __restrict__ bias,
                           const int* __restrict__ batch, float* __restrict__ pool,
                           int* __restrict__ pcnt) {
  __shared__ float pl[128];
  __shared__ int pc[64];
  int tid = threadIdx.x;
  if (tid < 128) pl[tid] = 0.f;
  if (tid < 64) pc[tid] = 0;
  __syncthreads();
  int node = blockIdx.x * 256 + tid;
  if (node < NN) {
    int s = rowp[node];
    int c = cnt[node];
    float a0 = 0.f, a1 = 0.f;
    for (int i = 0; i < c; i += 4) {
      int j0 = i, j1 = i + 1, j2 = i + 2, j3 = i + 3;
      int s0 = col[s + j0];
      int sA = col[s + (j1 < c ? j1 : j0)];
      int sB = col[s + (j2 < c ? j2 : j0)];
      int sC = col[s + (j3 < c ? j3 : j0)];
      float2 t0 = *(const float2*)(T2 + 2 * (size_t)s0);
      float2 t1 = *(const float2*)(T2 + 2 * (size_t)sA);
      float2 t2 = *(const float2*)(T2 + 2 * (size_t)sB);
      float2 t3 = *(const float2*)(T2 + 2 * (size_t)sC);
      float w1 = j1 < c ? 1.f : 0.f;
      float w2 = j2 < c ? 1.f : 0.f;
      float w3 = j3 < c ? 1.f : 0.f;
      a0 += t0.x; a1 += t0.y;
      a0 = fmaf(w1, t1.x, a0); a1 = fmaf(w1, t1.y, a1);
      a0 = fmaf(w2, t2.x, a0); a1 = fmaf(w2, t2.y, a1);
      a0 = fmaf(w3, t3.x, a0); a1 = fmaf(w3, t3.y, a1);
    }
    float di = dinv[node];
    float2 tn = *(const float2*)(T2 + 2 * (size_t)node);
    float v0 = (a0 + tn.x) * di + bias[0];
    float v1 = (a1 + tn.y) * di + bias[1];
    int bb = batch[node];
    atomicAdd(&pl[bb * 2 + 0], v0);
    atomicAdd(&pl[bb * 2 + 1], v1);
    atomicAdd(&pc[bb], 1);
  }
  __syncthreads();
  if (tid < 128 && pl[tid] != 0.f) unsafeAtomicAdd(&pool[tid], pl[tid]);
  if (tid < 64 && pc[tid] != 0) atomicAdd(&pcnt[tid], pc[tid]);
}

__global__ void k_div(const float* __restrict__ pool, const int* __restrict__ pcnt,
                      float* __restrict__ out) {
  int i = threadIdx.x;
  if (i < 128) {
    int c = pcnt[i >> 1];
    out[i] = pool[i] / (float)(c > 0 ? c : 1);
  }
}

extern "C" void kernel_launch(void* const* d_in, const int* in_sizes, int n_in,
                              void* d_out, int out_size, void* d_ws, size_t ws_size,
                              hipStream_t stream) {
  (void)in_sizes; (void)n_in; (void)out_size; (void)ws_size;
  const float* x     = (const float*)d_in[0];
  const float* W_in  = (const float*)d_in[1];
  const float* b_in  = (const float*)d_in[2];
  const float* W_h   = (const float*)d_in[3];
  const float* b_h   = (const float*)d_in[4];
  const float* W_out = (const float*)d_in[5];
  const float* b_out = (const float*)d_in[6];
  const float* gamma = (const float*)d_in[7];
  const float* beta  = (const float*)d_in[8];
  const int*   ei    = (const int*)d_in[9];
  const int*   batch = (const int*)d_in[10];
  const int* src = ei;
  const int* dst = ei + NE;
  float* out = (float*)d_out;

  char* w = (char*)d_ws;
  size_t off = 0;
  auto alloc = [&](size_t bytes) -> void* {
    void* p = (void*)(w + off);
    off += (bytes + 511) & ~(size_t)511;
    return p;
  };
  int*    deg   = (int*)alloc((size_t)NN * 4);
  int*    rowp  = (int*)alloc((size_t)NN * 4);
  int*    col   = (int*)alloc((size_t)NE * 4);
  float*  dinv  = (float*)alloc((size_t)NN * 4);
  int*    bbase = (int*)alloc((NBUCK + 1) * 4);
  int*    bcur  = (int*)alloc(NBUCK * 4);
  // zeroed zone: stats (3*128 dbl = 3072) | pool (512) | pcnt (256) | gbh (782*4 = 3128)
  char*   zzone = (char*)alloc(7168);
  double* stats = (double*)zzone;
  float*  pool  = (float*)(zzone + 3072);
  int*    pcnt  = (int*)(zzone + 3072 + 512);
  int*    gbh   = (int*)(zzone + 3840);
  float*  buf0  = (float*)alloc((size_t)NN * HID * 4);
  float*  buf1  = (float*)alloc((size_t)NN * HID * 4);
  float*  buf2  = (float*)alloc((size_t)NN * HID * 4);
  float*  T2    = (float*)alloc((size_t)NN * 2 * 4);
  // ebuf (9.6MB) aliases buf0: consumed by k_bucket_csr before buf0's first write
  unsigned long long* ebuf = (unsigned long long*)buf0;

  hipMemsetAsync(zzone, 0, 7040, stream);

  // graph prep: bucket-radix CSR build
  k_ehist<<<293, 256, 0, stream>>>(dst, gbh);
  k_escan<<<1, 256, 0, stream>>>(gbh, bbase, bcur);
  k_escatter<<<293, 256, 0, stream>>>(src, dst, bcur, ebuf);
  k_bucket_csr<<<NBUCK, 256, 0, stream>>>(ebuf, bbase, deg, rowp, dinv, col);

  const int mmgrid = (NN + 63) / 64;   // 1563

  // layer 1: x(128) -> T (pre-scaled) -> G1
  k_mmA<<<mmgrid, 256, 0, stream>>>(x, W_in, dinv, buf0, NN);
  k_agg64<<<(NN + 3) / 4, 256, 0, stream>>>(buf0, rowp, deg, col, dinv, b_in, buf1, 1);
  k_stats<<<512, 256, 0, stream>>>(buf1, stats);

  // layer 2: h1 = BN1(G1) (side-> buf2); T = h1@W_h0 -> buf0
  k_mmB<<<mmgrid, 256, 0, stream>>>(buf1, stats, gamma, beta, nullptr, buf2, W_h,
                                    dinv, buf0, NN);
  k_agg64<<<(NN + 3) / 4, 256, 0, stream>>>(buf0, rowp, deg, col, dinv, b_h, buf1, 1);
  k_stats<<<512, 256, 0, stream>>>(buf1, stats + 128);

  // layer 3: h2 = BN2(G2)+h1 (side-> buf0); T = h2@W_h1 -> buf1 (T aliases G: barrier-safe)
  k_mmB<<<mmgrid, 256, 0, stream>>>(buf1, stats + 128, gamma + 64, beta + 64, buf2,
                                    buf0, W_h + HID * HID, dinv, buf1, NN);
  k_agg64<<<(NN + 3) / 4, 256, 0, stream>>>(buf1, rowp, deg, col, dinv, b_h + HID, buf2, 1);
  k_stats<<<512, 256, 0, stream>>>(buf2, stats + 256);

  // output: h3 = BN3(G3)+h2 fused with mm 64->2 (T2 pre-scaled), then agg+pool fused
  k_bnmmout<<<(NN + 255) / 256, 256, 0, stream>>>(buf2, stats + 256, gamma + 128,
                                                  beta + 128, buf0, W_out, dinv, T2, NN);
  k_agg2pool<<<(NN + 255) / 256, 256, 0, stream>>>(T2, rowp, deg, col, dinv, b_out,
                                                   batch, pool, pcnt);
  k_div<<<1, 128, 0, stream>>>(pool, pcnt, out);
}

// Round 8
// 438.854 us; speedup vs baseline: 1.1616x; 1.1616x over previous
//
#include <hip/hip_runtime.h>

// EnhancedGNN on MI355X.
// R11: re-anchor at R7 (best measured 464us; R6/R10 reg-based mm rewrites and
//      R8/R9 stats fusion all regressed). Two safe increments: (1) k_stats
//      vectorized float4 (3->~5 TB/s), (2) k_div folded into k_agg2pool via
//      device ticket + atomic-read finalize (coherent across XCDs). 15 launches.

#define NN 100000
#define NE 1200000
#define NBATCH 64
#define IND 128
#define HID 64
#define EPSF 1e-5f
#define NBUCK 782   // ceil(100000/128)
#define NPB 128     // nodes per bucket; bucket(d) = d >> 7

// ---------------- graph prep: bucket histogram ----------------
__global__ void k_ehist(const int* __restrict__ dst, int* __restrict__ gbh) {
  __shared__ int lh[NBUCK];
  int tid = threadIdx.x;
  for (int i = tid; i < NBUCK; i += 256) lh[i] = 0;
  __syncthreads();
  int base = blockIdx.x * 4096;
#pragma unroll
  for (int j = 0; j < 16; j++) {
    int e = base + j * 256 + tid;
    if (e < NE) atomicAdd(&lh[dst[e] >> 7], 1);
  }
  __syncthreads();
  for (int i = tid; i < NBUCK; i += 256) {
    int v = lh[i];
    if (v) atomicAdd(&gbh[i], v);
  }
}

// exclusive scan of 782 bucket counts -> bbase[0..NBUCK], bcur=bbase
__global__ void k_escan(const int* __restrict__ gbh, int* __restrict__ bbase,
                        int* __restrict__ bcur) {
  __shared__ int a[256];
  int tid = threadIdx.x;
  int loc[4];
  int tsum = 0;
  for (int j = 0; j < 4; j++) {
    int idx = tid * 4 + j;
    int v = (idx < NBUCK) ? gbh[idx] : 0;
    loc[j] = tsum;
    tsum += v;
  }
  a[tid] = tsum;
  __syncthreads();
  for (int off = 1; off < 256; off <<= 1) {
    int v = (tid >= off) ? a[tid - off] : 0;
    __syncthreads();
    a[tid] += v;
    __syncthreads();
  }
  int excl = a[tid] - tsum;
  for (int j = 0; j < 4; j++) {
    int idx = tid * 4 + j;
    if (idx < NBUCK) {
      int v = excl + loc[j];
      bbase[idx] = v;
      bcur[idx] = v;
    }
  }
  if (tid == 255) bbase[NBUCK] = a[255];
}

// scatter (src,dst) pairs into bucket-contiguous ebuf; LDS-aggregated cursor grabs
__global__ void k_escatter(const int* __restrict__ src, const int* __restrict__ dst,
                           int* __restrict__ bcur, unsigned long long* __restrict__ ebuf) {
  __shared__ int lh[NBUCK];
  __shared__ int lbase[NBUCK];
  int tid = threadIdx.x;
  for (int i = tid; i < NBUCK; i += 256) lh[i] = 0;
  __syncthreads();
  int base = blockIdx.x * 4096;
  int sv[16], dv[16], rk[16];
#pragma unroll
  for (int j = 0; j < 16; j++) {
    int e = base + j * 256 + tid;
    if (e < NE) {
      sv[j] = src[e];
      dv[j] = dst[e];
      rk[j] = atomicAdd(&lh[dv[j] >> 7], 1);
    } else {
      dv[j] = -1;
    }
  }
  __syncthreads();
  for (int i = tid; i < NBUCK; i += 256) {
    int v = lh[i];
    lbase[i] = v ? atomicAdd(&bcur[i], v) : 0;
  }
  __syncthreads();
#pragma unroll
  for (int j = 0; j < 16; j++) {
    if (dv[j] >= 0) {
      int b = dv[j] >> 7;
      ebuf[lbase[b] + rk[j]] =
          (unsigned long long)(unsigned)sv[j] | ((unsigned long long)(unsigned)dv[j] << 32);
    }
  }
}

// one block per bucket: local hist -> deg/dinv, local scan -> rowp, LDS-cursor fill -> col
__global__ void k_bucket_csr(const unsigned long long* __restrict__ ebuf,
                             const int* __restrict__ bbase, int* __restrict__ deg,
                             int* __restrict__ rowp, float* __restrict__ dinv,
                             int* __restrict__ col) {
  __shared__ int ldeg[NPB];
  __shared__ int lcur[NPB];
  __shared__ int sred[NPB];
  int b = blockIdx.x, tid = threadIdx.x;
  int nbase = b * NPB;
  int e0 = bbase[b], e1 = bbase[b + 1];
  if (tid < NPB) ldeg[tid] = 0;
  __syncthreads();
  for (int e = e0 + tid; e < e1; e += 256) {
    int d = (int)(ebuf[e] >> 32) - nbase;
    atomicAdd(&ldeg[d], 1);
  }
  __syncthreads();
  if (tid < NPB) sred[tid] = ldeg[tid];
  __syncthreads();
  for (int off = 1; off < NPB; off <<= 1) {
    int v = 0;
    if (tid < NPB && tid >= off) v = sred[tid - off];
    __syncthreads();
    if (tid < NPB) sred[tid] += v;
    __syncthreads();
  }
  if (tid < NPB) {
    int excl = sred[tid] - ldeg[tid];
    lcur[tid] = excl;
    int gn = nbase + tid;
    if (gn < NN) {
      int dg = ldeg[tid];
      deg[gn] = dg;
      rowp[gn] = e0 + excl;
      dinv[gn] = rsqrtf((float)dg + 1.0f);
    }
  }
  __syncthreads();
  for (int e = e0 + tid; e < e1; e += 256) {
    unsigned long long p = ebuf[e];
    int s = (int)(unsigned)p;
    int d = (int)(p >> 32) - nbase;
    int r = atomicAdd(&lcur[d], 1);
    col[e0 + r] = s;
  }
}

// ---------------- mm A: X[nrows,128] @ W[128,64] -> T * dinv[row] --------------
// 64 rows/block, 4 threads/row (col-quarter per wave, readfirstlane -> s_load W).
__global__ __launch_bounds__(256) void k_mmA(const float* __restrict__ X,
                                             const float* __restrict__ W,
                                             const float* __restrict__ dinv,
                                             float* __restrict__ T, int nrows) {
  __shared__ float xs[64 * 65];
  int tid = threadIdx.x;
  int rbase = blockIdx.x * 64;
  int q4 = __builtin_amdgcn_readfirstlane(tid >> 6);  // wave-uniform col quarter
  int r = tid & 63;
  int r65 = r * 65;
  float4 acc[4];
#pragma unroll
  for (int j = 0; j < 4; j++) acc[j] = {0.f, 0.f, 0.f, 0.f};

  for (int ch = 0; ch < 2; ch++) {
#pragma unroll
    for (int i = 0; i < 4; i++) {
      int f = i * 256 + tid;
      int rr = f >> 4, kq = f & 15;
      int gr = rbase + rr;
      int grc = gr < nrows ? gr : nrows - 1;
      float4 v = *(const float4*)(X + (size_t)grc * 128 + ch * 64 + 4 * kq);
      float* p = xs + rr * 65 + 4 * kq;
      p[0] = v.x; p[1] = v.y; p[2] = v.z; p[3] = v.w;
    }
    __syncthreads();
    const float* Wb = W + ch * 64 * 64 + q4 * 16;
#pragma unroll 4
    for (int k = 0; k < 64; k++) {
      float xk = xs[r65 + k];
      const float4* wr = (const float4*)(Wb + (size_t)k * 64);
#pragma unroll
      for (int j = 0; j < 4; j++) {
        float4 wv = wr[j];
        acc[j].x = fmaf(xk, wv.x, acc[j].x);
        acc[j].y = fmaf(xk, wv.y, acc[j].y);
        acc[j].z = fmaf(xk, wv.z, acc[j].z);
        acc[j].w = fmaf(xk, wv.w, acc[j].w);
      }
    }
    if (ch == 0) __syncthreads();
  }

  int row = rbase + r;
  if (row < nrows) {
    float dv = dinv[row];
    float4* t4 = (float4*)(T + (size_t)row * 64 + q4 * 16);
#pragma unroll
    for (int j = 0; j < 4; j++) {
      float4 o = acc[j];
      o.x *= dv; o.y *= dv; o.z *= dv; o.w *= dv;
      t4[j] = o;
    }
  }
}

// ---------------- mm B: BN(G)(+res) -> Hside; T = (h @ W) * dinv[row] ----------
// Same 4-threads/row structure, K=64 (single stage); BN scale in-block from stats.
__global__ __launch_bounds__(256) void k_mmB(const float* __restrict__ G,
                                             const double* __restrict__ st,
                                             const float* __restrict__ gamma,
                                             const float* __restrict__ beta,
                                             const float* __restrict__ res,
                                             float* __restrict__ Hside,
                                             const float* __restrict__ W,
                                             const float* __restrict__ dinv,
                                             float* __restrict__ T, int nrows) {
  __shared__ float xs[64 * 65];
  __shared__ float scl[128];
  int tid = threadIdx.x;
  if (tid < 64) {
    double m = st[tid] / (double)NN;
    double var = st[64 + tid] / (double)NN - m * m;
    float scale = gamma[tid] * rsqrtf((float)var + EPSF);
    scl[tid] = scale;
    scl[64 + tid] = beta[tid] - (float)m * scale;
  }
  __syncthreads();

  int rbase = blockIdx.x * 64;
#pragma unroll
  for (int i = 0; i < 4; i++) {
    int f = i * 256 + tid;
    int rr = f >> 4, kq = f & 15;
    int gr = rbase + rr;
    int grc = gr < nrows ? gr : nrows - 1;
    int kof = 4 * kq;
    float4 v = *(const float4*)(G + (size_t)grc * 64 + kof);
    float4 s = ((const float4*)scl)[kq];
    float4 sh = ((const float4*)(scl + 64))[kq];
    v.x = v.x * s.x + sh.x;
    v.y = v.y * s.y + sh.y;
    v.z = v.z * s.z + sh.z;
    v.w = v.w * s.w + sh.w;
    if (res != nullptr) {
      float4 rr2 = *(const float4*)(res + (size_t)grc * 64 + kof);
      v.x += rr2.x; v.y += rr2.y; v.z += rr2.z; v.w += rr2.w;
    }
    if (gr < nrows) *(float4*)(Hside + (size_t)gr * 64 + kof) = v;
    float* p = xs + rr * 65 + kof;
    p[0] = v.x; p[1] = v.y; p[2] = v.z; p[3] = v.w;
  }
  __syncthreads();

  int q4 = __builtin_amdgcn_readfirstlane(tid >> 6);
  int r = tid & 63;
  int r65 = r * 65;
  float4 acc[4];
#pragma unroll
  for (int j = 0; j < 4; j++) acc[j] = {0.f, 0.f, 0.f, 0.f};
  const float* Wb = W + q4 * 16;
#pragma unroll 4
  for (int k = 0; k < 64; k++) {
    float xk = xs[r65 + k];
    const float4* wr = (const float4*)(Wb + (size_t)k * 64);
#pragma unroll
    for (int j = 0; j < 4; j++) {
      float4 wv = wr[j];
      acc[j].x = fmaf(xk, wv.x, acc[j].x);
      acc[j].y = fmaf(xk, wv.y, acc[j].y);
      acc[j].z = fmaf(xk, wv.z, acc[j].z);
      acc[j].w = fmaf(xk, wv.w, acc[j].w);
    }
  }

  int row = rbase + r;
  if (row < nrows) {
    float dv = dinv[row];
    float4* t4 = (float4*)(T + (size_t)row * 64 + q4 * 16);
#pragma unroll
    for (int j = 0; j < 4; j++) {
      float4 o = acc[j];
      o.x *= dv; o.y *= dv; o.z *= dv; o.w *= dv;
      t4[j] = o;
    }
  }
}

// ---------------- aggregation (HID=64): wave/node, 16 edges in flight --------------
// T is pre-scaled by dinv[row]: o = di*(sum T'[src] + T'[node]) + bias
__global__ void k_agg64(const float* __restrict__ T, const int* __restrict__ row_start,
                        const int* __restrict__ cnt, const int* __restrict__ col,
                        const float* __restrict__ dinv, const float* __restrict__ bias,
                        float* __restrict__ G, int relu) {
  int lane = threadIdx.x & 63;
  int wv = threadIdx.x >> 6;
  int node = blockIdx.x * 4 + wv;
  if (node >= NN) return;
  int grp = lane >> 4;
  int q = lane & 15;
  int s = row_start[node];
  int c = cnt[node];
  float4 acc = {0.f, 0.f, 0.f, 0.f};
  for (int i = 0; i < c; i += 16) {
    int j0 = i + grp, j1 = j0 + 4, j2 = j0 + 8, j3 = j0 + 12;
    int s0 = col[s + (j0 < c ? j0 : 0)];
    int s1 = col[s + (j1 < c ? j1 : 0)];
    int s2 = col[s + (j2 < c ? j2 : 0)];
    int s3 = col[s + (j3 < c ? j3 : 0)];
    float4 t0 = ((const float4*)(T + (size_t)s0 * 64))[q];
    float4 t1 = ((const float4*)(T + (size_t)s1 * 64))[q];
    float4 t2 = ((const float4*)(T + (size_t)s2 * 64))[q];
    float4 t3 = ((const float4*)(T + (size_t)s3 * 64))[q];
    float w0 = j0 < c ? 1.f : 0.f;
    float w1 = j1 < c ? 1.f : 0.f;
    float w2 = j2 < c ? 1.f : 0.f;
    float w3 = j3 < c ? 1.f : 0.f;
    acc.x = fmaf(w0, t0.x, acc.x); acc.y = fmaf(w0, t0.y, acc.y);
    acc.z = fmaf(w0, t0.z, acc.z); acc.w = fmaf(w0, t0.w, acc.w);
    acc.x = fmaf(w1, t1.x, acc.x); acc.y = fmaf(w1, t1.y, acc.y);
    acc.z = fmaf(w1, t1.z, acc.z); acc.w = fmaf(w1, t1.w, acc.w);
    acc.x = fmaf(w2, t2.x, acc.x); acc.y = fmaf(w2, t2.y, acc.y);
    acc.z = fmaf(w2, t2.z, acc.z); acc.w = fmaf(w2, t2.w, acc.w);
    acc.x = fmaf(w3, t3.x, acc.x); acc.y = fmaf(w3, t3.y, acc.y);
    acc.z = fmaf(w3, t3.z, acc.z); acc.w = fmaf(w3, t3.w, acc.w);
  }
  acc.x += __shfl_xor(acc.x, 16, 64);
  acc.y += __shfl_xor(acc.y, 16, 64);
  acc.z += __shfl_xor(acc.z, 16, 64);
  acc.w += __shfl_xor(acc.w, 16, 64);
  acc.x += __shfl_xor(acc.x, 32, 64);
  acc.y += __shfl_xor(acc.y, 32, 64);
  acc.z += __shfl_xor(acc.z, 32, 64);
  acc.w += __shfl_xor(acc.w, 32, 64);
  if (grp == 0) {
    float di = dinv[node];
    float4 ts = ((const float4*)(T + (size_t)node * 64))[q];
    float4 bs = ((const float4*)bias)[q];
    float4 o;
    o.x = (acc.x + ts.x) * di + bs.x;
    o.y = (acc.y + ts.y) * di + bs.y;
    o.z = (acc.z + ts.z) * di + bs.z;
    o.w = (acc.w + ts.w) * di + bs.w;
    if (relu) {
      o.x = fmaxf(o.x, 0.f);
      o.y = fmaxf(o.y, 0.f);
      o.z = fmaxf(o.z, 0.f);
      o.w = fmaxf(o.w, 0.f);
    }
    ((float4*)(G + (size_t)node * 64))[q] = o;
  }
}

// ---------------- BN stats (float4 vectorized) ----------------
__global__ __launch_bounds__(256) void k_stats(const float* __restrict__ H,
                                               double* __restrict__ st) {
  int q = threadIdx.x & 15;   // feature quarter (4 floats)
  int rg = threadIdx.x >> 4;  // 16 row-groups per block
  float4 s1 = {0.f, 0.f, 0.f, 0.f};
  float4 s2 = {0.f, 0.f, 0.f, 0.f};
  for (int r = blockIdx.x * 16 + rg; r < NN; r += gridDim.x * 16) {
    float4 v = *(const float4*)(H + (size_t)r * 64 + q * 4);
    s1.x += v.x; s1.y += v.y; s1.z += v.z; s1.w += v.w;
    s2.x = fmaf(v.x, v.x, s2.x); s2.y = fmaf(v.y, v.y, s2.y);
    s2.z = fmaf(v.z, v.z, s2.z); s2.w = fmaf(v.w, v.w, s2.w);
  }
  __shared__ float a[16][16][8];
  a[rg][q][0] = s1.x; a[rg][q][1] = s1.y; a[rg][q][2] = s1.z; a[rg][q][3] = s1.w;
  a[rg][q][4] = s2.x; a[rg][q][5] = s2.y; a[rg][q][6] = s2.z; a[rg][q][7] = s2.w;
  __syncthreads();
  int tid = threadIdx.x;
  if (tid < 128) {
    int f = tid & 63;        // feature
    int which = tid >> 6;    // 0 = sum, 1 = sumsq
    int qq = f >> 2, jj = (f & 3) + which * 4;
    float t = 0.f;
#pragma unroll
    for (int g = 0; g < 16; g++) t += a[g][qq][jj];
    unsafeAtomicAdd(&st[which * 64 + f], (double)t);
  }
}

// ---------------- fused: BN3 (in-block scale) + residual + matmul 64->2, T2 *= dinv --
__global__ void k_bnmmout(const float* __restrict__ G, const double* __restrict__ st,
                          const float* __restrict__ gamma, const float* __restrict__ beta,
                          const float* __restrict__ res, const float* __restrict__ W,
                          const float* __restrict__ dinv, float* __restrict__ T2,
                          int nrows) {
  __shared__ float Wl[128];
  __shared__ float scl[128];
  int tid = threadIdx.x;
  if (tid < 32) ((float4*)Wl)[tid] = ((const float4*)W)[tid];
  else if (tid >= 64 && tid < 128) {
    int f = tid - 64;
    double m = st[f] / (double)NN;
    double var = st[64 + f] / (double)NN - m * m;
    float scale = gamma[f] * rsqrtf((float)var + EPSF);
    scl[f] = scale;
    scl[64 + f] = beta[f] - (float)m * scale;
  }
  __syncthreads();
  int row = blockIdx.x * 256 + tid;
  if (row >= nrows) return;
  const float4* g4 = (const float4*)(G + (size_t)row * 64);
  const float4* r4 = (const float4*)(res + (size_t)row * 64);
  float a0 = 0.f, a1 = 0.f;
#pragma unroll
  for (int q = 0; q < 16; q++) {
    float4 v = g4[q];
    float4 rr = r4[q];
    float4 s = ((const float4*)scl)[q];
    float4 sh = ((const float4*)(scl + 64))[q];
    float h0 = v.x * s.x + sh.x + rr.x;
    float h1 = v.y * s.y + sh.y + rr.y;
    float h2 = v.z * s.z + sh.z + rr.z;
    float h3 = v.w * s.w + sh.w + rr.w;
    const float* wk = Wl + q * 8;
    a0 = fmaf(h0, wk[0], a0); a1 = fmaf(h0, wk[1], a1);
    a0 = fmaf(h1, wk[2], a0); a1 = fmaf(h1, wk[3], a1);
    a0 = fmaf(h2, wk[4], a0); a1 = fmaf(h2, wk[5], a1);
    a0 = fmaf(h3, wk[6], a0); a1 = fmaf(h3, wk[7], a1);
  }
  float dv = dinv[row];
  T2[(size_t)row * 2 + 0] = a0 * dv;
  T2[(size_t)row * 2 + 1] = a1 * dv;
}

// ---- fused final aggregation (dim 2, T2 pre-scaled) + pool + ticket finalize ----
__global__ void k_agg2pool(const float* __restrict__ T2, const int* __restrict__ rowp,
                           const int* __restrict__ cnt, const int* __restrict__ col,
                           const float* __restrict__ dinv, const float* __restrict__ bias,
                           const int* __restrict__ batch, float* __restrict__ pool,
                           int* __restrict__ pcnt, int* __restrict__ tick,
                           float* __restrict__ out, int nblk) {
  __shared__ float pl[128];
  __shared__ int pc[64];
  __shared__ int lastflag;
  int tid = threadIdx.x;
  if (tid < 128) pl[tid] = 0.f;
  if (tid < 64) pc[tid] = 0;
  __syncthreads();
  int node = blockIdx.x * 256 + tid;
  if (node < NN) {
    int s = rowp[node];
    int c = cnt[node];
    float a0 = 0.f, a1 = 0.f;
    for (int i = 0; i < c; i += 4) {
      int j0 = i, j1 = i + 1, j2 = i + 2, j3 = i + 3;
      int s0 = col[s + j0];
      int sA = col[s + (j1 < c ? j1 : j0)];
      int sB = col[s + (j2 < c ? j2 : j0)];
      int sC = col[s + (j3 < c ? j3 : j0)];
      float2 t0 = *(const float2*)(T2 + 2 * (size_t)s0);
      float2 t1 = *(const float2*)(T2 + 2 * (size_t)sA);
      float2 t2 = *(const float2*)(T2 + 2 * (size_t)sB);
      float2 t3 = *(const float2*)(T2 + 2 * (size_t)sC);
      float w1 = j1 < c ? 1.f : 0.f;
      float w2 = j2 < c ? 1.f : 0.f;
      float w3 = j3 < c ? 1.f : 0.f;
      a0 += t0.x; a1 += t0.y;
      a0 = fmaf(w1, t1.x, a0); a1 = fmaf(w1, t1.y, a1);
      a0 = fmaf(w2, t2.x, a0); a1 = fmaf(w2, t2.y, a1);
      a0 = fmaf(w3, t3.x, a0); a1 = fmaf(w3, t3.y, a1);
    }
    float di = dinv[node];
    float2 tn = *(const float2*)(T2 + 2 * (size_t)node);
    float v0 = (a0 + tn.x) * di + bias[0];
    float v1 = (a1 + tn.y) * di + bias[1];
    int bb = batch[node];
    atomicAdd(&pl[bb * 2 + 0], v0);
    atomicAdd(&pl[bb * 2 + 1], v1);
    atomicAdd(&pc[bb], 1);
  }
  __syncthreads();
  if (tid < 128 && pl[tid] != 0.f) unsafeAtomicAdd(&pool[tid], pl[tid]);
  if (tid < 64 && pc[tid] != 0) atomicAdd(&pcnt[tid], pc[tid]);
  // ticket: last block to finish reads back (atomically, cross-XCD coherent) and divides
  __syncthreads();
  if (tid == 0) {
    __threadfence();
    int old = atomicAdd(tick, 1);
    lastflag = (old == nblk - 1) ? 1 : 0;
  }
  __syncthreads();
  if (lastflag && tid < 128) {
    float v = unsafeAtomicAdd(&pool[tid], 0.f);       // coherent read
    int c = atomicAdd(&pcnt[tid >> 1], 0);            // coherent read
    out[tid] = v / (float)(c > 0 ? c : 1);
  }
}

extern "C" void kernel_launch(void* const* d_in, const int* in_sizes, int n_in,
                              void* d_out, int out_size, void* d_ws, size_t ws_size,
                              hipStream_t stream) {
  (void)in_sizes; (void)n_in; (void)out_size; (void)ws_size;
  const float* x     = (const float*)d_in[0];
  const float* W_in  = (const float*)d_in[1];
  const float* b_in  = (const float*)d_in[2];
  const float* W_h   = (const float*)d_in[3];
  const float* b_h   = (const float*)d_in[4];
  const float* W_out = (const float*)d_in[5];
  const float* b_out = (const float*)d_in[6];
  const float* gamma = (const float*)d_in[7];
  const float* beta  = (const float*)d_in[8];
  const int*   ei    = (const int*)d_in[9];
  const int*   batch = (const int*)d_in[10];
  const int* src = ei;
  const int* dst = ei + NE;
  float* out = (float*)d_out;

  char* w = (char*)d_ws;
  size_t off = 0;
  auto alloc = [&](size_t bytes) -> void* {
    void* p = (void*)(w + off);
    off += (bytes + 511) & ~(size_t)511;
    return p;
  };
  int*    deg   = (int*)alloc((size_t)NN * 4);
  int*    rowp  = (int*)alloc((size_t)NN * 4);
  int*    col   = (int*)alloc((size_t)NE * 4);
  float*  dinv  = (float*)alloc((size_t)NN * 4);
  int*    bbase = (int*)alloc((NBUCK + 1) * 4);
  int*    bcur  = (int*)alloc(NBUCK * 4);
  // zeroed zone: stats (3*128 dbl = 3072) | pool (512) | pcnt (256) | tick (256) |
  //              gbh (782*4 = 3128) -> 7224 bytes
  char*   zzone = (char*)alloc(7680);
  double* stats = (double*)zzone;
  float*  pool  = (float*)(zzone + 3072);
  int*    pcnt  = (int*)(zzone + 3584);
  int*    tick  = (int*)(zzone + 3840);
  int*    gbh   = (int*)(zzone + 4096);
  float*  buf0  = (float*)alloc((size_t)NN * HID * 4);
  float*  buf1  = (float*)alloc((size_t)NN * HID * 4);
  float*  buf2  = (float*)alloc((size_t)NN * HID * 4);
  float*  T2    = (float*)alloc((size_t)NN * 2 * 4);
  // ebuf (9.6MB) aliases buf0: consumed by k_bucket_csr before buf0's first write
  unsigned long long* ebuf = (unsigned long long*)buf0;

  hipMemsetAsync(zzone, 0, 7424, stream);

  // graph prep: bucket-radix CSR build
  k_ehist<<<293, 256, 0, stream>>>(dst, gbh);
  k_escan<<<1, 256, 0, stream>>>(gbh, bbase, bcur);
  k_escatter<<<293, 256, 0, stream>>>(src, dst, bcur, ebuf);
  k_bucket_csr<<<NBUCK, 256, 0, stream>>>(ebuf, bbase, deg, rowp, dinv, col);

  const int mmgrid = (NN + 63) / 64;   // 1563

  // layer 1: x(128) -> T (pre-scaled) -> G1
  k_mmA<<<mmgrid, 256, 0, stream>>>(x, W_in, dinv, buf0, NN);
  k_agg64<<<(NN + 3) / 4, 256, 0, stream>>>(buf0, rowp, deg, col, dinv, b_in, buf1, 1);
  k_stats<<<512, 256, 0, stream>>>(buf1, stats);

  // layer 2: h1 = BN1(G1) (side-> buf2); T = h1@W_h0 -> buf0
  k_mmB<<<mmgrid, 256, 0, stream>>>(buf1, stats, gamma, beta, nullptr, buf2, W_h,
                                    dinv, buf0, NN);
  k_agg64<<<(NN + 3) / 4, 256, 0, stream>>>(buf0, rowp, deg, col, dinv, b_h, buf1, 1);
  k_stats<<<512, 256, 0, stream>>>(buf1, stats + 128);

  // layer 3: h2 = BN2(G2)+h1 (side-> buf0); T = h2@W_h1 -> buf1 (T aliases G: per-block safe)
  k_mmB<<<mmgrid, 256, 0, stream>>>(buf1, stats + 128, gamma + 64, beta + 64, buf2,
                                    buf0, W_h + HID * HID, dinv, buf1, NN);
  k_agg64<<<(NN + 3) / 4, 256, 0, stream>>>(buf1, rowp, deg, col, dinv, b_h + HID, buf2, 1);
  k_stats<<<512, 256, 0, stream>>>(buf2, stats + 256);

  // output: h3 = BN3(G3)+h2 fused with mm 64->2 (T2 pre-scaled), then agg+pool+div fused
  k_bnmmout<<<(NN + 255) / 256, 256, 0, stream>>>(buf2, stats + 256, gamma + 128,
                                                  beta + 128, buf0, W_out, dinv, T2, NN);
  const int pgrid = (NN + 255) / 256;  // 391
  k_agg2pool<<<pgrid, 256, 0, stream>>>(T2, rowp, deg, col, dinv, b_out, batch, pool,
                                        pcnt, tick, out, pgrid);
}